// Round 8
// baseline (136.967 us; speedup 1.0000x reference)
//
#include <hip/hip_runtime.h>
#include <math.h>

// NGRU via MFMA, R8 = R7 + amdgpu_waves_per_eu(2,2) spill fix.
// Only layer 1 of the 2 parallel GRU layers contributes (reference returns
// h_final[-1]); layer 0 is skipped.
//
// Shapes: x (64,48,256,64) f32; Wih/Whh (2,192,64); bih/bhh (2,192).
// rows = B*N = 16384 independent GRU sequences, T=48, H=64.
//
// Structure: 512 blocks x 256 threads (4 waves), 32 rows/block, 2 blocks/CU.
// R7 lesson: __launch_bounds__(...,2) is only a MINIMUM waves/EU — the
// allocator targeted 4 waves/EU (128 VGPR) and spilled 13 MB/step of the
// ~190-reg working set to scratch (VGPR_Count=128, WRITE_SIZE 17.4MB).
// amdgpu_waves_per_eu(2,2) clamps min=max=2 -> full 256-VGPR budget at the
// same residency R5 had. Verify via VGPR_Count ~180-210, WRITE_SIZE 4MB.
//
// Wave nw owns output columns j in [16nw,16nw+16) for ALL FOUR gates
// (g=0:r, 1:z, 2:gin, 3:ghn) -> gate epilogue fully register-local.
//  * x is NOT recurrent -> each thread loads its x MFMA-fragments straight
//    from global into REGISTERS (prefetched during step t-1's epilogue) and
//    converts privately. x vanishes from LDS: -8 ds_read, -2 ds_write per
//    thread/step; the 36 x-part MFMAs issue right after the barrier with
//    zero LDS latency, hiding the h-part ds_read latency. L2 absorbs the
//    4x intra-block re-read.
//  * Gate biases preloaded into the MFMA accumulators: -32 epilogue adds.
//  * LDS: h-only bf16 hi/lo planes [32][HK=72], ping-ponged, lo-plane
//    staggered +16 shorts == +8 banks -> paired h dword writes (even lane
//    hi-plane, odd lane lo-plane) hit all 32 banks 2-way = free.
//
// Split-bf16: v = hi + lo; product = AhBh + AhBl + AlBh (~2^-17 rel).

#define TT 48
#define HH 64
#define GG 192
#define NN 256
#define RPB 32          // rows per block
#define NTHREADS 256    // 4 waves
#define HK 72           // h row stride in shorts (64 + 8 pad)
#define PLANE (RPB*HK + 16)  // 2320 shorts; +16 = +8 banks lo-plane stagger
#define ABUF (2*PLANE)

typedef __attribute__((ext_vector_type(8))) short bs8;       // 8 bf16
typedef __attribute__((ext_vector_type(4))) float f32x4;     // MFMA accum
typedef __attribute__((ext_vector_type(4))) unsigned u32x4;

__device__ __forceinline__ float sigm(float v) {
    return __builtin_amdgcn_rcpf(1.f + __expf(-v));
}
__device__ __forceinline__ float tanh_f(float v) {
    float a = fabsf(v);
    float e = __expf(2.f * a);
    float t = 1.f - 2.f * __builtin_amdgcn_rcpf(e + 1.f);
    return v < 0.f ? -t : t;
}
// packed f32x2 -> bf16x2 (RNE): D[15:0]=bf16(S0), D[31:16]=bf16(S1)
__device__ __forceinline__ unsigned cvtpk(float lo, float hi) {
    unsigned r;
    asm("v_cvt_pk_bf16_f32 %0, %1, %2" : "=v"(r) : "v"(lo), "v"(hi));
    return r;
}
__device__ __forceinline__ float ubits(unsigned u) { return __uint_as_float(u); }
// scalar RNE helpers (B build only; one-time)
__device__ __forceinline__ unsigned short f2bf(float f) {
    unsigned u = __float_as_uint(f);
    return (unsigned short)((u + 0x7fffu + ((u >> 16) & 1u)) >> 16);
}
__device__ __forceinline__ float bf2f(unsigned short b) {
    return __uint_as_float(((unsigned)b) << 16);
}
// 8 consecutive f32 -> bf16 hi/lo fragments
__device__ __forceinline__ void cvt8(float4 a, float4 b, bs8& h8, bs8& l8) {
    unsigned h0 = cvtpk(a.x, a.y), h1 = cvtpk(a.z, a.w);
    unsigned h2 = cvtpk(b.x, b.y), h3 = cvtpk(b.z, b.w);
    unsigned l0 = cvtpk(a.x - ubits(h0 << 16), a.y - ubits(h0 & 0xffff0000u));
    unsigned l1 = cvtpk(a.z - ubits(h1 << 16), a.w - ubits(h1 & 0xffff0000u));
    unsigned l2 = cvtpk(b.x - ubits(h2 << 16), b.y - ubits(h2 & 0xffff0000u));
    unsigned l3 = cvtpk(b.z - ubits(h3 << 16), b.w - ubits(h3 & 0xffff0000u));
    h8 = __builtin_bit_cast(bs8, (u32x4){h0, h1, h2, h3});
    l8 = __builtin_bit_cast(bs8, (u32x4){l0, l1, l2, l3});
}

#define MFMA3(ACC, AH, AL, S)                                                   \
    ACC = __builtin_amdgcn_mfma_f32_16x16x32_bf16(AH, Bh[S], ACC, 0, 0, 0);     \
    ACC = __builtin_amdgcn_mfma_f32_16x16x32_bf16(AH, Bl[S], ACC, 0, 0, 0);     \
    ACC = __builtin_amdgcn_mfma_f32_16x16x32_bf16(AL, Bh[S], ACC, 0, 0, 0);

__global__ __launch_bounds__(NTHREADS)
__attribute__((amdgpu_waves_per_eu(2, 2)))
void ngru_mfma8(const float* __restrict__ x,
                const float* __restrict__ Wih,
                const float* __restrict__ Whh,
                const float* __restrict__ bih,
                const float* __restrict__ bhh,
                float* __restrict__ out)
{
    extern __shared__ __align__(16) short lds_s[];   // 2 x ABUF shorts (h only)

    const int tid  = threadIdx.x;
    const int lane = tid & 63;
    const int nw   = tid >> 6;          // wave 0..3 -> j slice [16nw,16nw+16)
    const int c0   = lane & 15;         // C col within tile / A row index
    const int rq   = lane >> 4;         // quarter-wave
    const int j    = nw * 16 + c0;
    const bool odd = (c0 & 1);

    const int grow0 = blockIdx.x * RPB;
    const int bb    = grow0 / NN;
    const int n0    = grow0 % NN;

    const float* Wi = Wih + GG * HH;    // layer 1
    const float* Wh = Whh + GG * HH;

    // ---- B fragments in registers: 12 kt-slots (zero tiles skipped) ----
    bs8 Bh[12], Bl[12];
    #pragma unroll
    for (int g = 0; g < 4; ++g) {
        const int ktlo = (g == 3) ? 2 : 0;
        const int kthi = (g == 2) ? 2 : 4;
        #pragma unroll
        for (int kt = ktlo; kt < kthi; ++kt) {
            const int slot = (g < 2) ? g * 4 + kt : 8 + (g - 2) * 2 + (kt & 1);
            const bool isWi = (kt < 2);
            const int gbase = (g >= 2) ? 2 : g;
            const float* src = (isWi ? Wi : Wh)
                             + (gbase * 64 + j) * HH + (kt & 1) * 32 + rq * 8;
            bs8 h8, l8;
            #pragma unroll
            for (int q = 0; q < 8; ++q) {
                float v = src[q];
                unsigned short hb = f2bf(v);
                unsigned short lb = f2bf(v - bf2f(hb));
                h8[q] = (short)hb; l8[q] = (short)lb;
            }
            Bh[slot] = h8; Bl[slot] = l8;
        }
    }

    // ---- biases (layer 1), r/z pre-summed; n biases stay separate ----
    const float brz  = bih[GG + j]      + bhh[GG + j];
    const float bzz  = bih[GG + 64 + j] + bhh[GG + 64 + j];
    const float bi_n = bih[GG + 128 + j];
    const float bh_n = bhh[GG + 128 + j];

    // ---- init: zero h region of buf0 (both planes) ----
    {
        const int zr = tid >> 3;          // 0..31
        const int zc = (tid & 7) * 8;     // 0..56
        bs8 z = {0,0,0,0,0,0,0,0};
        *(bs8*)(lds_s + zr * HK + zc)         = z;
        *(bs8*)(lds_s + PLANE + zr * HK + zc) = z;
    }

    // ---- x fragment registers for the CURRENT step (load t=0 now) ----
    // frag (m,kt): A rows m*16+c0, k = kt*32 + rq*8 .. +8
    bs8 Xh[2][2], Xl[2][2];
    {
        const float* xb = x + ((size_t)(bb * TT) * NN + n0) * HH;
        #pragma unroll
        for (int m = 0; m < 2; ++m)
            #pragma unroll
            for (int kt = 0; kt < 2; ++kt) {
                const float* src = xb + (m * 16 + c0) * HH + kt * 32 + rq * 8;
                float4 a = *(const float4*)src;
                float4 b = *(const float4*)(src + 4);
                cvt8(a, b, Xh[m][kt], Xl[m][kt]);
            }
    }

    float hreg[2][4];
    #pragma unroll
    for (int m = 0; m < 2; ++m)
        #pragma unroll
        for (int r = 0; r < 4; ++r) hreg[m][r] = 0.f;

    __syncthreads();   // buf0 h-region ready for t=0

    for (int t = 0; t < TT; ++t) {
        short* cur = lds_s + (t & 1) * ABUF;
        short* nxt = lds_s + ((t & 1) ^ 1) * ABUF;
        const bool hasNext = (t + 1 < TT);

        // acc preloaded with biases (constant across the 4 C-regs of a tile)
        f32x4 acc[2][4];
        #pragma unroll
        for (int m = 0; m < 2; ++m) {
            acc[m][0] = (f32x4){brz,  brz,  brz,  brz };
            acc[m][1] = (f32x4){bzz,  bzz,  bzz,  bzz };
            acc[m][2] = (f32x4){bi_n, bi_n, bi_n, bi_n};
            acc[m][3] = (f32x4){bh_n, bh_n, bh_n, bh_n};
        }

        // issue h-part A reads first (latency overlaps x-part MFMAs)
        bs8 Hh[2][2], Hl[2][2];
        #pragma unroll
        for (int m = 0; m < 2; ++m)
            #pragma unroll
            for (int kt = 0; kt < 2; ++kt) {
                const short* ab = cur + (m * 16 + c0) * HK + kt * 32 + rq * 8;
                Hh[m][kt] = *(const bs8*)ab;
                Hl[m][kt] = *(const bs8*)(ab + PLANE);
            }

        __builtin_amdgcn_s_setprio(1);
        // x-part MFMAs from registers: gates r, z, gin (zero LDS latency)
        #pragma unroll
        for (int m = 0; m < 2; ++m)
            #pragma unroll
            for (int kt = 0; kt < 2; ++kt) {
                MFMA3(acc[m][0], Xh[m][kt], Xl[m][kt], kt);       // r
                MFMA3(acc[m][1], Xh[m][kt], Xl[m][kt], 4 + kt);   // z
                MFMA3(acc[m][2], Xh[m][kt], Xl[m][kt], 8 + kt);   // gin
            }
        // h-part MFMAs: gates r, z, ghn
        #pragma unroll
        for (int m = 0; m < 2; ++m)
            #pragma unroll
            for (int kt = 0; kt < 2; ++kt) {
                MFMA3(acc[m][0], Hh[m][kt], Hl[m][kt], 2 + kt);   // r
                MFMA3(acc[m][1], Hh[m][kt], Hl[m][kt], 6 + kt);   // z
                MFMA3(acc[m][3], Hh[m][kt], Hl[m][kt], 10 + kt);  // ghn
            }
        __builtin_amdgcn_s_setprio(0);

        // prefetch x(t+1) into registers (latency hides under epilogue)
        float4 pa[2][2], pb[2][2];
        if (hasNext) {
            const float* xb = x + ((size_t)(bb * TT + t + 1) * NN + n0) * HH;
            #pragma unroll
            for (int m = 0; m < 2; ++m)
                #pragma unroll
                for (int kt = 0; kt < 2; ++kt) {
                    const float* src = xb + (m * 16 + c0) * HH + kt * 32 + rq * 8;
                    pa[m][kt] = *(const float4*)src;
                    pb[m][kt] = *(const float4*)(src + 4);
                }
        }

        // ===== epilogue: register-local gates; h -> nxt buffer =====
        short* hp = nxt + (odd ? PLANE : 0);
        #pragma unroll
        for (int m = 0; m < 2; ++m) {
            #pragma unroll
            for (int r = 0; r < 4; ++r) {
                const int row = m * 16 + rq * 4 + r;
                float rg = sigm(acc[m][0][r]);
                float zg = sigm(acc[m][1][r]);
                float ng = tanh_f(fmaf(rg, acc[m][3][r], acc[m][2][r]));
                float hn = fmaf(zg, hreg[m][r] - ng, ng);   // (1-z)n + z h
                hreg[m][r] = hn;
                if (hasNext) {
                    // paired dword write: even lane -> hi-plane dword {j,j+1},
                    // odd lane -> lo-plane dword; planes staggered 8 banks
                    // -> combined 64-lane write covers 32 banks 2-way (free)
                    float partner = __shfl_xor(hn, 1);
                    float ve = odd ? partner : hn;     // value at even column
                    float vo = odd ? hn : partner;     // value at odd column
                    unsigned hd = cvtpk(ve, vo);
                    float re = ve - ubits(hd << 16);
                    float ro = vo - ubits(hd & 0xffff0000u);
                    unsigned ld = cvtpk(re, ro);
                    unsigned w = odd ? ld : hd;
                    *(unsigned*)(hp + row * HK + (j & ~1)) = w;
                }
            }
        }

        if (hasNext) {
            // convert x(t+1) into fragment registers (global latency elapsed)
            #pragma unroll
            for (int m = 0; m < 2; ++m)
                #pragma unroll
                for (int kt = 0; kt < 2; ++kt)
                    cvt8(pa[m][kt], pb[m][kt], Xh[m][kt], Xl[m][kt]);
            __syncthreads();   // nxt h ready for step t+1
        }
    }

    #pragma unroll
    for (int m = 0; m < 2; ++m)
        #pragma unroll
        for (int r = 0; r < 4; ++r)
            out[(size_t)(grow0 + m * 16 + rq * 4 + r) * HH + j] = hreg[m][r];
}

extern "C" void kernel_launch(void* const* d_in, const int* in_sizes, int n_in,
                              void* d_out, int out_size, void* d_ws, size_t ws_size,
                              hipStream_t stream) {
    const float* x   = (const float*)d_in[0];
    const float* Wih = (const float*)d_in[1];
    const float* Whh = (const float*)d_in[2];
    const float* bih = (const float*)d_in[3];
    const float* bhh = (const float*)d_in[4];
    float* out = (float*)d_out;

    const int lds_bytes = 2 * ABUF * (int)sizeof(short);   // 18,560 B
    (void)hipFuncSetAttribute((const void*)ngru_mfma8,
                        hipFuncAttributeMaxDynamicSharedMemorySize, lds_bytes);

    dim3 grid(16384 / RPB);     // 512 blocks, 2 per CU
    dim3 block(NTHREADS);
    ngru_mfma8<<<grid, block, lds_bytes, stream>>>(x, Wih, Whh, bih, bhh, out);
}

// Round 9
// 67.900 us; speedup vs baseline: 2.0172x; 2.0172x over previous
//
#include <hip/hip_runtime.h>
#include <math.h>

// NGRU via MFMA, R9 = R5 shell + single-product FP16 MFMA.
// Only layer 1 of the 2 parallel GRU layers contributes (reference returns
// h_final[-1]); layer 0 is skipped.
//
// Shapes: x (64,48,256,64) f32; Wih/Whh (2,192,64); bih/bhh (2,192).
// rows = B*N = 16384 independent GRU sequences, T=48, H=64.
//
// KEY CHANGE vs R5: the 3-product split-bf16 scheme (2^-17 rel err) was
// over-engineered — the observed absmax (0.00390625, identical since the
// R0 fp32 kernel) is dominated by the shared fast-math sigm/tanh, not the
// matmul. fp16 gives 2^-11 in ONE product: |W|<=0.125, |h|<1, |x|~N(0,1)
// all fp16-safe; propagated h-error ~3e-4 << 2^-8. MFMA count 72 -> 24
// per wave/step (~2800 -> ~930 cyc/SIMD MFMA phase), B-frags 96 -> 48
// VGPRs, A planes 2 -> 1 (8 ds_read_b128/wave/step), h-write is a plain
// ds_write_b16 (no shfl/pack), conversions ~3x cheaper.
//
// Structure (R5, proven): 512 blocks x 256 threads (4 waves), 32 rows per
// block, 2 blocks/CU (2 barrier domains). Wave nw owns output columns
// j in [16nw,16nw+16) for ALL FOUR gates (r, z, gin, ghn) -> gate epilogue
// fully register-local. Zero B-tiles skipped: 12 kt-slots.
// A = [x_t | h_{t-1}] fp16 [32][AK=136], ping-ponged -> ONE barrier/step.
// Biases preloaded into the MFMA accumulators.
// waves_per_eu(2,2): full 256-VGPR budget at the grid-fixed 2-blocks/CU
// residency (R7 lesson: a 128-cap makes the allocator spill; R8 verified
// the clamp removes scratch traffic).

#define TT 48
#define HH 64
#define GG 192
#define NN 256
#define RPB 32          // rows per block
#define NTHREADS 256    // 4 waves
#define AK 136          // A row stride in halfs (128 + 8 pad; 16B-aligned rows)
#define HBUF (RPB*AK)   // halfs per A buffer (4352)

typedef _Float16 h8 __attribute__((ext_vector_type(8)));   // 8 fp16 (4 VGPRs)
typedef __attribute__((ext_vector_type(4))) float f32x4;   // MFMA accum
typedef __attribute__((ext_vector_type(4))) unsigned u32x4;

__device__ __forceinline__ float sigm(float v) {
    return __builtin_amdgcn_rcpf(1.f + __expf(-v));
}
__device__ __forceinline__ float tanh_f(float v) {
    float a = fabsf(v);
    float e = __expf(2.f * a);
    float t = 1.f - 2.f * __builtin_amdgcn_rcpf(e + 1.f);
    return v < 0.f ? -t : t;
}
// pack 2 f32 -> dword of 2 fp16 (RNE via v_cvt_f16_f32 + v_pack_b32_f16)
__device__ __forceinline__ unsigned pkh2(float a, float b) {
    union { _Float16 h[2]; unsigned u; } c;
    c.h[0] = (_Float16)a; c.h[1] = (_Float16)b;
    return c.u;
}

__global__ __launch_bounds__(NTHREADS)
__attribute__((amdgpu_waves_per_eu(2, 2)))
void ngru_mfma9(const float* __restrict__ x,
                const float* __restrict__ Wih,
                const float* __restrict__ Whh,
                const float* __restrict__ bih,
                const float* __restrict__ bhh,
                float* __restrict__ out)
{
    extern __shared__ __align__(16) _Float16 lds_h[];  // 2 x HBUF halfs

    const int tid  = threadIdx.x;
    const int lane = tid & 63;
    const int nw   = tid >> 6;          // wave 0..3 -> j slice [16nw,16nw+16)
    const int c0   = lane & 15;         // C col within tile / A row index
    const int rq   = lane >> 4;         // quarter-wave
    const int j    = nw * 16 + c0;

    const int grow0 = blockIdx.x * RPB;
    const int bb    = grow0 / NN;
    const int n0    = grow0 % NN;

    const float* Wi = Wih + GG * HH;    // layer 1
    const float* Wh = Whh + GG * HH;

    // ---- B fragments in registers: 12 kt-slots (zero tiles skipped) ----
    // slot: g<2 -> g*4+kt (kt 0..3, kt<2 = Wi, kt>=2 = Wh);
    //       g==2 -> 8+kt (kt 0..1, Wi gate-n); g==3 -> 10+(kt&1) (Wh gate-n)
    h8 Bf[12];
    #pragma unroll
    for (int g = 0; g < 4; ++g) {
        const int ktlo = (g == 3) ? 2 : 0;
        const int kthi = (g == 2) ? 2 : 4;
        #pragma unroll
        for (int kt = ktlo; kt < kthi; ++kt) {
            const int slot = (g < 2) ? g * 4 + kt : 8 + (g - 2) * 2 + (kt & 1);
            const bool isWi = (kt < 2);
            const int gbase = (g >= 2) ? 2 : g;
            const float* src = (isWi ? Wi : Wh)
                             + (gbase * 64 + j) * HH + (kt & 1) * 32 + rq * 8;
            h8 f;
            #pragma unroll
            for (int q = 0; q < 8; ++q) f[q] = (_Float16)src[q];
            Bf[slot] = f;
        }
    }

    // ---- biases (layer 1), r/z pre-summed; n biases stay separate ----
    const float brz  = bih[GG + j]      + bhh[GG + j];
    const float bzz  = bih[GG + 64 + j] + bhh[GG + 64 + j];
    const float bi_n = bih[GG + 128 + j];
    const float bh_n = bhh[GG + 128 + j];

    // ---- init buf0: zero h region, stage x_0 ----
    const int xrow = tid >> 3;          // 0..31
    const int xkc  = (tid & 7) * 8;     // half offset 0,8,...,56
    {
        *(u32x4*)(lds_h + xrow * AK + 64 + xkc) = (u32x4){0u, 0u, 0u, 0u};

        const float* xsrc = x + ((size_t)(bb * TT) * NN + n0 + xrow) * HH + xkc;
        float4 p0 = *(const float4*)xsrc;
        float4 p1 = *(const float4*)(xsrc + 4);
        u32x4 w = {pkh2(p0.x, p0.y), pkh2(p0.z, p0.w),
                   pkh2(p1.x, p1.y), pkh2(p1.z, p1.w)};
        *(u32x4*)(lds_h + xrow * AK + xkc) = w;
    }

    float hreg[2][4];
    #pragma unroll
    for (int m = 0; m < 2; ++m)
        #pragma unroll
        for (int r = 0; r < 4; ++r) hreg[m][r] = 0.f;

    __syncthreads();   // buf0 ready for t=0

    for (int t = 0; t < TT; ++t) {
        _Float16* cur = lds_h + (t & 1) * HBUF;
        _Float16* nxt = lds_h + ((t & 1) ^ 1) * HBUF;
        const bool hasNext = (t + 1 < TT);

        // prefetch x_{t+1} (HBM/L3 latency hides under MFMA + epilogue)
        float4 p0, p1;
        if (hasNext) {
            const float* xsrc =
                x + ((size_t)(bb * TT + t + 1) * NN + n0 + xrow) * HH + xkc;
            p0 = *(const float4*)xsrc;
            p1 = *(const float4*)(xsrc + 4);
        }

        // acc preloaded with biases (constant across the 4 C-regs of a tile)
        f32x4 acc[2][4];
        #pragma unroll
        for (int m = 0; m < 2; ++m) {
            acc[m][0] = (f32x4){brz,  brz,  brz,  brz };
            acc[m][1] = (f32x4){bzz,  bzz,  bzz,  bzz };
            acc[m][2] = (f32x4){bi_n, bi_n, bi_n, bi_n};
            acc[m][3] = (f32x4){bh_n, bh_n, bh_n, bh_n};
        }

        // ===== MFMA: 4 gate-tiles x 2 m-tiles, single fp16 product =====
        __builtin_amdgcn_s_setprio(1);
        #pragma unroll
        for (int m = 0; m < 2; ++m) {
            const _Float16* ab = cur + (m * 16 + c0) * AK + rq * 8;
            h8 A_[4];
            #pragma unroll
            for (int kt = 0; kt < 4; ++kt)
                A_[kt] = *(const h8*)(ab + kt * 32);
            #pragma unroll
            for (int g = 0; g < 4; ++g) {
                #pragma unroll
                for (int kt = 0; kt < 4; ++kt) {
                    if ((g == 2 && kt >= 2) || (g == 3 && kt < 2)) continue;
                    const int slot = (g < 2) ? g * 4 + kt
                                             : 8 + (g - 2) * 2 + (kt & 1);
                    acc[m][g] = __builtin_amdgcn_mfma_f32_16x16x32_f16(
                        A_[kt], Bf[slot], acc[m][g], 0, 0, 0);
                }
            }
        }
        __builtin_amdgcn_s_setprio(0);

        // ===== epilogue: register-local gates; h -> nxt buffer =====
        #pragma unroll
        for (int m = 0; m < 2; ++m) {
            #pragma unroll
            for (int r = 0; r < 4; ++r) {
                const int row = m * 16 + rq * 4 + r;
                float rg = sigm(acc[m][0][r]);
                float zg = sigm(acc[m][1][r]);
                float ng = tanh_f(fmaf(rg, acc[m][3][r], acc[m][2][r]));
                float hn = fmaf(zg, hreg[m][r] - ng, ng);   // (1-z)n + z h
                hreg[m][r] = hn;
                if (hasNext)
                    nxt[row * AK + 64 + j] = (_Float16)hn;   // ds_write_b16
            }
        }

        if (hasNext) {
            u32x4 w = {pkh2(p0.x, p0.y), pkh2(p0.z, p0.w),
                       pkh2(p1.x, p1.y), pkh2(p1.z, p1.w)};
            *(u32x4*)(nxt + xrow * AK + xkc) = w;
            __syncthreads();   // nxt (h_t + x_{t+1}) ready for step t+1
        }
    }

    #pragma unroll
    for (int m = 0; m < 2; ++m)
        #pragma unroll
        for (int r = 0; r < 4; ++r)
            out[(size_t)(grow0 + m * 16 + rq * 4 + r) * HH + j] = hreg[m][r];
}

extern "C" void kernel_launch(void* const* d_in, const int* in_sizes, int n_in,
                              void* d_out, int out_size, void* d_ws, size_t ws_size,
                              hipStream_t stream) {
    const float* x   = (const float*)d_in[0];
    const float* Wih = (const float*)d_in[1];
    const float* Whh = (const float*)d_in[2];
    const float* bih = (const float*)d_in[3];
    const float* bhh = (const float*)d_in[4];
    float* out = (float*)d_out;

    const int lds_bytes = 2 * HBUF * (int)sizeof(_Float16);   // 17,408 B
    (void)hipFuncSetAttribute((const void*)ngru_mfma9,
                        hipFuncAttributeMaxDynamicSharedMemorySize, lds_bytes);

    dim3 grid(16384 / RPB);     // 512 blocks, 2 per CU
    dim3 block(NTHREADS);
    ngru_mfma9<<<grid, block, lds_bytes, stream>>>(x, Wih, Whh, bih, bhh, out);
}